// Round 2
// baseline (136.760 us; speedup 1.0000x reference)
//
#include <hip/hip_runtime.h>
#include <hip/hip_bf16.h>
#include <stdint.h>

#define NBATCH 16
#define NT 2048
#define NC 64
#define QT 64
#define KT 128
#define SC_LOG2E 11.5415603f  // 8 * log2(e)

typedef __bf16 bf16x8 __attribute__((ext_vector_type(8)));
typedef float f32x4 __attribute__((ext_vector_type(4)));

extern "C" __device__ float __ocml_exp2_f32(float);

static __device__ __forceinline__ unsigned short f2bf(float f) {
  __bf16 h = (__bf16)f;  // hardware RTNE convert
  union { __bf16 h; unsigned short u; } a; a.h = h; return a.u;
}
static __device__ __forceinline__ float bf2f(unsigned short h) {
  union { uint32_t u; float f; } a; a.u = ((uint32_t)h) << 16;
  return a.f;
}

// ---------------------------------------------------------------------------
// Kernel 1: q,k,v projections. 64 rows per block.
// Outputs: khi/klo/qhi/qlo as [B*T][64] bf16 (hi/lo split), vt as [B][64][T] bf16.
// ---------------------------------------------------------------------------
__global__ __launch_bounds__(256, 2) void proj_kernel(
    const float* __restrict__ x,
    const float* __restrict__ Wk, const float* __restrict__ bk,
    const float* __restrict__ Wq, const float* __restrict__ bq,
    const float* __restrict__ Wv, const float* __restrict__ bv,
    unsigned short* __restrict__ khi, unsigned short* __restrict__ klo,
    unsigned short* __restrict__ qhi, unsigned short* __restrict__ qlo,
    unsigned short* __restrict__ vt)
{
  __shared__ __align__(16) char smem[65536];
  const int XH = 0, XL = 8192, WTH = 16384, WTL = 40960, VTB = 0; // VTB aliases XH
  const int tid = (int)threadIdx.x;
  const int l = tid & 63, w = tid >> 6;
  const int lr = l & 15, lg = l >> 4;
  const int blk = (int)blockIdx.x;
  const int rowbase = blk * 64;
  const int bb = blk >> 5;          // 32 blocks per batch

  // stage x tile (64x64 f32) as hi/lo bf16, swizzled
  for (int c = tid; c < 1024; c += 256) {
    int row = c >> 4, d0 = (c & 15) * 4;
    const float4 xv = *(const float4*)(x + (size_t)(rowbase + row) * NC + d0);
    unsigned short h0 = f2bf(xv.x), h1 = f2bf(xv.y), h2 = f2bf(xv.z), h3 = f2bf(xv.w);
    unsigned short m0 = f2bf(xv.x - bf2f(h0)), m1 = f2bf(xv.y - bf2f(h1));
    unsigned short m2 = f2bf(xv.z - bf2f(h2)), m3 = f2bf(xv.w - bf2f(h3));
    uint2 ph, pl;
    ph.x = (uint32_t)h0 | ((uint32_t)h1 << 16); ph.y = (uint32_t)h2 | ((uint32_t)h3 << 16);
    pl.x = (uint32_t)m0 | ((uint32_t)m1 << 16); pl.y = (uint32_t)m2 | ((uint32_t)m3 << 16);
    int byteoff = (row * 128 + d0 * 2) ^ ((row & 7) << 4);
    *(uint2*)(smem + XH + byteoff) = ph;
    *(uint2*)(smem + XL + byteoff) = pl;
  }
  // stage W^T (192 og-rows x 64 c-cols) as hi/lo bf16, swizzled
  for (int cw = tid; cw < 3072; cw += 256) {
    int og = cw >> 4, c0 = (cw & 15) * 4;
    const float* Wm = (og < 64) ? Wk : (og < 128 ? Wq : Wv);
    int o = og & 63;
    float w0 = Wm[(size_t)(c0 + 0) * 64 + o];
    float w1 = Wm[(size_t)(c0 + 1) * 64 + o];
    float w2 = Wm[(size_t)(c0 + 2) * 64 + o];
    float w3 = Wm[(size_t)(c0 + 3) * 64 + o];
    unsigned short h0 = f2bf(w0), h1 = f2bf(w1), h2 = f2bf(w2), h3 = f2bf(w3);
    unsigned short m0 = f2bf(w0 - bf2f(h0)), m1 = f2bf(w1 - bf2f(h1));
    unsigned short m2 = f2bf(w2 - bf2f(h2)), m3 = f2bf(w3 - bf2f(h3));
    uint2 ph, pl;
    ph.x = (uint32_t)h0 | ((uint32_t)h1 << 16); ph.y = (uint32_t)h2 | ((uint32_t)h3 << 16);
    pl.x = (uint32_t)m0 | ((uint32_t)m1 << 16); pl.y = (uint32_t)m2 | ((uint32_t)m3 << 16);
    int byteoff = (og * 128 + c0 * 2) ^ ((og & 7) << 4);
    *(uint2*)(smem + WTH + byteoff) = ph;
    *(uint2*)(smem + WTL + byteoff) = pl;
  }
  __syncthreads();

  // A-frags for this wave's 16 rows
  bf16x8 Ah[2], Al[2];
  {
    int row = w * 16 + lr;
#pragma unroll
    for (int dc = 0; dc < 2; ++dc) {
      int byteoff = (row * 128 + (dc * 32 + lg * 8) * 2) ^ ((row & 7) << 4);
      Ah[dc] = *(const bf16x8*)(smem + XH + byteoff);
      Al[dc] = *(const bf16x8*)(smem + XL + byteoff);
    }
  }
  f32x4 acc[12];
#pragma unroll
  for (int nb = 0; nb < 12; ++nb) {
    f32x4 a = {0.f, 0.f, 0.f, 0.f};
    int og = nb * 16 + lr;
#pragma unroll
    for (int dc = 0; dc < 2; ++dc) {
      int byteoff = (og * 128 + (dc * 32 + lg * 8) * 2) ^ ((og & 7) << 4);
      bf16x8 bh = *(const bf16x8*)(smem + WTH + byteoff);
      bf16x8 bl = *(const bf16x8*)(smem + WTL + byteoff);
      a = __builtin_amdgcn_mfma_f32_16x16x32_bf16(Ah[dc], bh, a, 0, 0, 0);
      a = __builtin_amdgcn_mfma_f32_16x16x32_bf16(Al[dc], bh, a, 0, 0, 0);
      a = __builtin_amdgcn_mfma_f32_16x16x32_bf16(Ah[dc], bl, a, 0, 0, 0);
    }
    acc[nb] = a;
  }
  __syncthreads();  // done reading XH/XL; VTB may now alias

  // epilogue: bias add, hi/lo split out for k/q, v into LDS transpose buffer
#pragma unroll
  for (int nb = 0; nb < 12; ++nb) {
    int og = nb * 16 + lr;
    const float* bp = (og < 64) ? bk : (og < 128 ? bq : bv);
    float bias = bp[og & 63];
#pragma unroll
    for (int r = 0; r < 4; ++r) {
      float val = acc[nb][r] + bias;
      int tloc = w * 16 + lg * 4 + r;
      size_t gt = (size_t)(rowbase + tloc);
      if (og < 64) {
        unsigned short h = f2bf(val);
        khi[gt * 64 + og] = h;
        klo[gt * 64 + og] = f2bf(val - bf2f(h));
      } else if (og < 128) {
        unsigned short h = f2bf(val);
        qhi[gt * 64 + (og - 64)] = h;
        qlo[gt * 64 + (og - 64)] = f2bf(val - bf2f(h));
      } else {
        int o = og - 128;
        int byteoff = (o * 128 + tloc * 2) ^ ((o & 7) << 4);
        *(unsigned short*)(smem + VTB + byteoff) = f2bf(val);
      }
    }
  }
  __syncthreads();
  // copy v^T tile [64 o][64 t] to global [B][64][T]
  for (int cc = tid; cc < 512; cc += 256) {
    int o = cc >> 3, t0 = (cc & 7) * 8;
    int byteoff = (o * 128 + t0 * 2) ^ ((o & 7) << 4);
    uint4 v = *(const uint4*)(smem + VTB + byteoff);
    *(uint4*)(vt + ((size_t)bb * 64 + o) * NT + (size_t)(blk & 31) * 64 + t0) = v;
  }
}

// ---------------------------------------------------------------------------
// Kernel 2: flash attention. QT=64 -> 512 blocks (2 blocks/CU), 4 waves.
// Dedicated P region (2 barriers/iter). T14 register prefetch of next K/V tile.
// ---------------------------------------------------------------------------
__global__ __launch_bounds__(256, 2) void attn_kernel(
    const unsigned short* __restrict__ khi, const unsigned short* __restrict__ klo,
    const unsigned short* __restrict__ qhi, const unsigned short* __restrict__ qlo,
    const unsigned short* __restrict__ vt,
    float* __restrict__ out)
{
  __shared__ __align__(16) char smem[65536];
  const int KHI = 0, KLO = 16384, VTB = 32768, PB = 49152;
  const int tid = (int)threadIdx.x;
  const int l = tid & 63, w = tid >> 6;
  const int lr = l & 15, lg = l >> 4;
  // XCD-aware swizzle: 512 blocks, 8 XCDs -> each XCD gets 2 whole batches
  const int lb = ((int)(blockIdx.x & 7) << 6) | ((int)blockIdx.x >> 3);
  const int bb = lb >> 5;
  const int qt = lb & 31;

  const unsigned short* kh_base = khi + (size_t)bb * NT * 64;
  const unsigned short* kl_base = klo + (size_t)bb * NT * 64;
  const unsigned short* v_base  = vt + (size_t)bb * 64 * NT;

  // --- T14 prefetch regs for K/V tile 0 (issued before anything else)
  uint4 rKh[4], rKl[4], rV[4];
#pragma unroll
  for (int k2 = 0; k2 < 4; ++k2) {
    int c = tid + k2 * 256;
    rKh[k2] = *(const uint4*)((const char*)kh_base + c * 16);
    rKl[k2] = *(const uint4*)((const char*)kl_base + c * 16);
    int o = c >> 4, k0 = (c & 15) * 8;
    rV[k2] = *(const uint4*)(v_base + (size_t)o * NT + k0);
  }

  // --- Q prologue: stage 64x64 hi/lo into KHI/KLO, hoist frags to registers
  {
    const unsigned short* srcH = qhi + ((size_t)bb * NT + (size_t)qt * QT) * 64;
    const unsigned short* srcL = qlo + ((size_t)bb * NT + (size_t)qt * QT) * 64;
    for (int c = tid; c < 512; c += 256) {
      int row = c >> 3;
      int byteoff = (c * 16) ^ ((row & 7) << 4);
      *(uint4*)(smem + KHI + byteoff) = *(const uint4*)((const char*)srcH + c * 16);
      *(uint4*)(smem + KLO + byteoff) = *(const uint4*)((const char*)srcL + c * 16);
    }
  }
  __syncthreads();
  bf16x8 Qh[2], Ql[2];
  {
    int row = w * 16 + lr;
#pragma unroll
    for (int dc = 0; dc < 2; ++dc) {
      int byteoff = (row * 128 + (dc * 32 + lg * 8) * 2) ^ ((row & 7) << 4);
      Qh[dc] = *(const bf16x8*)(smem + KHI + byteoff);
      Ql[dc] = *(const bf16x8*)(smem + KLO + byteoff);
    }
  }
  __syncthreads();  // Q frag reads done before K writes overwrite the region

  f32x4 O[4];
#pragma unroll
  for (int nb = 0; nb < 4; ++nb) O[nb] = {0.f, 0.f, 0.f, 0.f};
  float mrun = -1e30f;
  float lrun = 0.f;

  for (int it = 0; it < NT / KT; ++it) {
    // write LDS from prefetched regs (compiler inserts vmcnt waits)
#pragma unroll
    for (int k2 = 0; k2 < 4; ++k2) {
      int c = tid + k2 * 256;
      int bo = (c * 16) ^ (((c >> 3) & 7) << 4);
      *(uint4*)(smem + KHI + bo) = rKh[k2];
      *(uint4*)(smem + KLO + bo) = rKl[k2];
      int bov = (c * 16) ^ (((c >> 4) & 7) << 4);
      *(uint4*)(smem + VTB + bov) = rV[k2];
    }
    // issue next tile's loads (stay in flight across the compute phase)
    if (it + 1 < NT / KT) {
      const char* nKh = (const char*)kh_base + (size_t)(it + 1) * KT * 128;
      const char* nKl = (const char*)kl_base + (size_t)(it + 1) * KT * 128;
      const unsigned short* nV = v_base + (size_t)(it + 1) * KT;
#pragma unroll
      for (int k2 = 0; k2 < 4; ++k2) {
        int c = tid + k2 * 256;
        rKh[k2] = *(const uint4*)(nKh + c * 16);
        rKl[k2] = *(const uint4*)(nKl + c * 16);
        int o = c >> 4, k0 = (c & 15) * 8;
        rV[k2] = *(const uint4*)(nV + (size_t)o * NT + k0);
      }
    }
    __syncthreads();  // staged tile visible to all waves

    // S^T[key][qrow] = K · Q^T, 3-term hi/lo split
    f32x4 S[8];
    __builtin_amdgcn_s_setprio(1);
#pragma unroll
    for (int kb = 0; kb < 8; ++kb) {
      int krow = kb * 16 + lr;
      bf16x8 Ah[2], Al[2];
#pragma unroll
      for (int dc = 0; dc < 2; ++dc) {
        int byteoff = (krow * 128 + (dc * 32 + lg * 8) * 2) ^ ((krow & 7) << 4);
        Ah[dc] = *(const bf16x8*)(smem + KHI + byteoff);
        Al[dc] = *(const bf16x8*)(smem + KLO + byteoff);
      }
      f32x4 a = {0.f, 0.f, 0.f, 0.f};
#pragma unroll
      for (int dc = 0; dc < 2; ++dc) {
        a = __builtin_amdgcn_mfma_f32_16x16x32_bf16(Ah[dc], Qh[dc], a, 0, 0, 0);
        a = __builtin_amdgcn_mfma_f32_16x16x32_bf16(Al[dc], Qh[dc], a, 0, 0, 0);
        a = __builtin_amdgcn_mfma_f32_16x16x32_bf16(Ah[dc], Ql[dc], a, 0, 0, 0);
      }
      S[kb] = a;
    }
    __builtin_amdgcn_s_setprio(0);

    // online softmax; stats at lane (l&15)=qrow
    float mt = -1e30f;
#pragma unroll
    for (int kb = 0; kb < 8; ++kb)
#pragma unroll
      for (int r = 0; r < 4; ++r) mt = fmaxf(mt, S[kb][r]);
    mt = fmaxf(mt, __shfl_xor(mt, 16));
    mt = fmaxf(mt, __shfl_xor(mt, 32));
    float mnew = fmaxf(mrun, mt);
    float alpha = __ocml_exp2_f32((mrun - mnew) * SC_LOG2E);
    mrun = mnew;
    float ts = 0.f;
    int prow = lr;
#pragma unroll
    for (int kb = 0; kb < 8; ++kb) {
      float p0 = __ocml_exp2_f32((S[kb][0] - mnew) * SC_LOG2E);
      float p1 = __ocml_exp2_f32((S[kb][1] - mnew) * SC_LOG2E);
      float p2 = __ocml_exp2_f32((S[kb][2] - mnew) * SC_LOG2E);
      float p3 = __ocml_exp2_f32((S[kb][3] - mnew) * SC_LOG2E);
      ts += (p0 + p1) + (p2 + p3);
      uint2 pk;
      pk.x = (uint32_t)f2bf(p0) | ((uint32_t)f2bf(p1) << 16);
      pk.y = (uint32_t)f2bf(p2) | ((uint32_t)f2bf(p3) << 16);
      int byteoff = (prow * 256 + kb * 32 + lg * 8) ^ ((prow & 7) << 4);
      *(uint2*)(smem + PB + w * 4096 + byteoff) = pk;
    }
    ts += __shfl_xor(ts, 16);
    ts += __shfl_xor(ts, 32);
    lrun = lrun * alpha + ts;
    // rescale O (O rows are lg*4+r; alpha lives at lane&15=row)
    float ar[4];
#pragma unroll
    for (int r = 0; r < 4; ++r) ar[r] = __shfl(alpha, (l & 48) + lg * 4 + r);
#pragma unroll
    for (int nb = 0; nb < 4; ++nb)
#pragma unroll
      for (int r = 0; r < 4; ++r) O[nb][r] *= ar[r];

    asm volatile("s_waitcnt lgkmcnt(0)" ::: "memory");  // wave-private P ready
    __builtin_amdgcn_sched_barrier(0);

    // O += P · V   (A = P [qrow][key], B = V via V^T [d][key])
    __builtin_amdgcn_s_setprio(1);
#pragma unroll
    for (int kc = 0; kc < 4; ++kc) {
      bf16x8 Ap;
      {
        int byteoff = (prow * 256 + kc * 64 + lg * 16) ^ ((prow & 7) << 4);
        Ap = *(const bf16x8*)(smem + PB + w * 4096 + byteoff);
      }
      bf16x8 Bv[4];
#pragma unroll
      for (int nb = 0; nb < 4; ++nb) {
        int drow = nb * 16 + lr;
        int byteoff = (drow * 256 + kc * 64 + lg * 16) ^ ((drow & 7) << 4);
        Bv[nb] = *(const bf16x8*)(smem + VTB + byteoff);
      }
#pragma unroll
      for (int nb = 0; nb < 4; ++nb)
        O[nb] = __builtin_amdgcn_mfma_f32_16x16x32_bf16(Ap, Bv[nb], O[nb], 0, 0, 0);
    }
    __builtin_amdgcn_s_setprio(0);
    __syncthreads();  // all waves done reading K/V/P before next overwrite
  }

  // epilogue: O / l, write f32
  {
    float inv = 1.0f / lrun;
    float ir[4];
#pragma unroll
    for (int r = 0; r < 4; ++r) ir[r] = __shfl(inv, (l & 48) + lg * 4 + r);
#pragma unroll
    for (int nb = 0; nb < 4; ++nb) {
      int d = nb * 16 + lr;
#pragma unroll
      for (int r = 0; r < 4; ++r) {
        int t = qt * QT + w * 16 + lg * 4 + r;
        out[((size_t)bb * NT + t) * 64 + d] = O[nb][r] * ir[r];
      }
    }
  }
}

extern "C" void kernel_launch(void* const* d_in, const int* in_sizes, int n_in,
                              void* d_out, int out_size, void* d_ws, size_t ws_size,
                              hipStream_t stream) {
  const float* x  = (const float*)d_in[0];
  const float* Wk = (const float*)d_in[1];
  const float* bk = (const float*)d_in[2];
  const float* Wq = (const float*)d_in[3];
  const float* bq = (const float*)d_in[4];
  const float* Wv = (const float*)d_in[5];
  const float* bv = (const float*)d_in[6];
  float* out = (float*)d_out;

  const size_t NE = (size_t)NBATCH * NT * 64;
  unsigned short* ws = (unsigned short*)d_ws;
  unsigned short* khi = ws;
  unsigned short* klo = ws + NE;
  unsigned short* qhi = ws + 2 * NE;
  unsigned short* qlo = ws + 3 * NE;
  unsigned short* vt  = ws + 4 * NE;

  proj_kernel<<<dim3((NBATCH * NT) / 64), dim3(256), 0, stream>>>(
      x, Wk, bk, Wq, bq, Wv, bv, khi, klo, qhi, qlo, vt);
  attn_kernel<<<dim3(NBATCH * (NT / QT)), dim3(256), 0, stream>>>(
      khi, klo, qhi, qlo, vt, out);
}

// Round 3
// 79.949 us; speedup vs baseline: 1.7106x; 1.7106x over previous
//
#include <hip/hip_runtime.h>
#include <hip/hip_bf16.h>
#include <stdint.h>

#define NBATCH 16
#define NT 2048
#define NC 64
#define QT 128
#define KT 128
#define SC_LOG2E 11.5415603f  // 8 * log2(e)

typedef __bf16 bf16x8 __attribute__((ext_vector_type(8)));
typedef float f32x4 __attribute__((ext_vector_type(4)));

extern "C" __device__ float __ocml_exp2_f32(float);

static __device__ __forceinline__ unsigned short f2bf(float f) {
  __bf16 h = (__bf16)f;  // hardware RTNE convert
  union { __bf16 h; unsigned short u; } a; a.h = h; return a.u;
}
static __device__ __forceinline__ float bf2f(unsigned short h) {
  union { uint32_t u; float f; } a; a.u = ((uint32_t)h) << 16;
  return a.f;
}

#define GLD_LDS16(gsrc, ldst)                                                  \
  __builtin_amdgcn_global_load_lds(                                            \
      (const __attribute__((address_space(1))) void*)(gsrc),                   \
      (__attribute__((address_space(3))) void*)(ldst), 16, 0, 0)

// ---------------------------------------------------------------------------
// Kernel 1: q,k,v projections. 64 rows per block. (unchanged from round 1)
// Outputs: khi/klo/qhi/qlo as [B*T][64] bf16 (hi/lo split), vt as [B][64][T].
// ---------------------------------------------------------------------------
__global__ __launch_bounds__(256, 2) void proj_kernel(
    const float* __restrict__ x,
    const float* __restrict__ Wk, const float* __restrict__ bk,
    const float* __restrict__ Wq, const float* __restrict__ bq,
    const float* __restrict__ Wv, const float* __restrict__ bv,
    unsigned short* __restrict__ khi, unsigned short* __restrict__ klo,
    unsigned short* __restrict__ qhi, unsigned short* __restrict__ qlo,
    unsigned short* __restrict__ vt)
{
  __shared__ __align__(16) char smem[65536];
  const int XH = 0, XL = 8192, WTH = 16384, WTL = 40960, VTB = 0; // VTB aliases XH
  const int tid = (int)threadIdx.x;
  const int l = tid & 63, w = tid >> 6;
  const int lr = l & 15, lg = l >> 4;
  const int blk = (int)blockIdx.x;
  const int rowbase = blk * 64;
  const int bb = blk >> 5;          // 32 blocks per batch

  for (int c = tid; c < 1024; c += 256) {
    int row = c >> 4, d0 = (c & 15) * 4;
    const float4 xv = *(const float4*)(x + (size_t)(rowbase + row) * NC + d0);
    unsigned short h0 = f2bf(xv.x), h1 = f2bf(xv.y), h2 = f2bf(xv.z), h3 = f2bf(xv.w);
    unsigned short m0 = f2bf(xv.x - bf2f(h0)), m1 = f2bf(xv.y - bf2f(h1));
    unsigned short m2 = f2bf(xv.z - bf2f(h2)), m3 = f2bf(xv.w - bf2f(h3));
    uint2 ph, pl;
    ph.x = (uint32_t)h0 | ((uint32_t)h1 << 16); ph.y = (uint32_t)h2 | ((uint32_t)h3 << 16);
    pl.x = (uint32_t)m0 | ((uint32_t)m1 << 16); pl.y = (uint32_t)m2 | ((uint32_t)m3 << 16);
    int byteoff = (row * 128 + d0 * 2) ^ ((row & 7) << 4);
    *(uint2*)(smem + XH + byteoff) = ph;
    *(uint2*)(smem + XL + byteoff) = pl;
  }
  for (int cw = tid; cw < 3072; cw += 256) {
    int og = cw >> 4, c0 = (cw & 15) * 4;
    const float* Wm = (og < 64) ? Wk : (og < 128 ? Wq : Wv);
    int o = og & 63;
    float w0 = Wm[(size_t)(c0 + 0) * 64 + o];
    float w1 = Wm[(size_t)(c0 + 1) * 64 + o];
    float w2 = Wm[(size_t)(c0 + 2) * 64 + o];
    float w3 = Wm[(size_t)(c0 + 3) * 64 + o];
    unsigned short h0 = f2bf(w0), h1 = f2bf(w1), h2 = f2bf(w2), h3 = f2bf(w3);
    unsigned short m0 = f2bf(w0 - bf2f(h0)), m1 = f2bf(w1 - bf2f(h1));
    unsigned short m2 = f2bf(w2 - bf2f(h2)), m3 = f2bf(w3 - bf2f(h3));
    uint2 ph, pl;
    ph.x = (uint32_t)h0 | ((uint32_t)h1 << 16); ph.y = (uint32_t)h2 | ((uint32_t)h3 << 16);
    pl.x = (uint32_t)m0 | ((uint32_t)m1 << 16); pl.y = (uint32_t)m2 | ((uint32_t)m3 << 16);
    int byteoff = (og * 128 + c0 * 2) ^ ((og & 7) << 4);
    *(uint2*)(smem + WTH + byteoff) = ph;
    *(uint2*)(smem + WTL + byteoff) = pl;
  }
  __syncthreads();

  bf16x8 Ah[2], Al[2];
  {
    int row = w * 16 + lr;
#pragma unroll
    for (int dc = 0; dc < 2; ++dc) {
      int byteoff = (row * 128 + (dc * 32 + lg * 8) * 2) ^ ((row & 7) << 4);
      Ah[dc] = *(const bf16x8*)(smem + XH + byteoff);
      Al[dc] = *(const bf16x8*)(smem + XL + byteoff);
    }
  }
  f32x4 acc[12];
#pragma unroll
  for (int nb = 0; nb < 12; ++nb) {
    f32x4 a = {0.f, 0.f, 0.f, 0.f};
    int og = nb * 16 + lr;
#pragma unroll
    for (int dc = 0; dc < 2; ++dc) {
      int byteoff = (og * 128 + (dc * 32 + lg * 8) * 2) ^ ((og & 7) << 4);
      bf16x8 bh = *(const bf16x8*)(smem + WTH + byteoff);
      bf16x8 bl = *(const bf16x8*)(smem + WTL + byteoff);
      a = __builtin_amdgcn_mfma_f32_16x16x32_bf16(Ah[dc], bh, a, 0, 0, 0);
      a = __builtin_amdgcn_mfma_f32_16x16x32_bf16(Al[dc], bh, a, 0, 0, 0);
      a = __builtin_amdgcn_mfma_f32_16x16x32_bf16(Ah[dc], bl, a, 0, 0, 0);
    }
    acc[nb] = a;
  }
  __syncthreads();  // done reading XH/XL; VTB may now alias

#pragma unroll
  for (int nb = 0; nb < 12; ++nb) {
    int og = nb * 16 + lr;
    const float* bp = (og < 64) ? bk : (og < 128 ? bq : bv);
    float bias = bp[og & 63];
#pragma unroll
    for (int r = 0; r < 4; ++r) {
      float val = acc[nb][r] + bias;
      int tloc = w * 16 + lg * 4 + r;
      size_t gt = (size_t)(rowbase + tloc);
      if (og < 64) {
        unsigned short h = f2bf(val);
        khi[gt * 64 + og] = h;
        klo[gt * 64 + og] = f2bf(val - bf2f(h));
      } else if (og < 128) {
        unsigned short h = f2bf(val);
        qhi[gt * 64 + (og - 64)] = h;
        qlo[gt * 64 + (og - 64)] = f2bf(val - bf2f(h));
      } else {
        int o = og - 128;
        int byteoff = (o * 128 + tloc * 2) ^ ((o & 7) << 4);
        *(unsigned short*)(smem + VTB + byteoff) = f2bf(val);
      }
    }
  }
  __syncthreads();
  for (int cc = tid; cc < 512; cc += 256) {
    int o = cc >> 3, t0 = (cc & 7) * 8;
    int byteoff = (o * 128 + t0 * 2) ^ ((o & 7) << 4);
    uint4 v = *(const uint4*)(smem + VTB + byteoff);
    *(uint4*)(vt + ((size_t)bb * 64 + o) * NT + (size_t)(blk & 31) * 64 + t0) = v;
  }
}

// ---------------------------------------------------------------------------
// Kernel 2: flash attention. QT=128, 512 threads (8 waves), grid 256.
// Double-buffered K/V via global_load_lds (pre-swizzled source), 1 raw
// s_barrier + vmcnt(0)-after-compute per iter (catalog 2-phase T3 pipeline).
// ---------------------------------------------------------------------------
__global__ __launch_bounds__(512, 2) void attn_kernel(
    const unsigned short* __restrict__ khi, const unsigned short* __restrict__ klo,
    const unsigned short* __restrict__ qhi, const unsigned short* __restrict__ qlo,
    const unsigned short* __restrict__ vt,
    float* __restrict__ out)
{
  __shared__ __align__(16) char smem[131072];
  const int BUF = 49152;                    // per-buffer: KHI 16K | KLO 16K | VT 16K
  const int PB = 98304;                     // P: 8 waves x 4KB
  const int tid = (int)threadIdx.x;
  const int l = tid & 63, w = tid >> 6;     // w in 0..7
  const int lr = l & 15, lg = l >> 4;
  // XCD-aware swizzle: 256 blocks -> 2 whole batches per XCD
  const int lb = ((int)(blockIdx.x & 7) << 5) | ((int)blockIdx.x >> 3);
  const int bb = lb >> 4;
  const int qt = lb & 15;

  const char* kh_base = (const char*)(khi + (size_t)bb * NT * 64);
  const char* kl_base = (const char*)(klo + (size_t)bb * NT * 64);
  const char* v_base  = (const char*)(vt + (size_t)bb * 64 * NT);

  // --- Q fragments direct global -> registers (rows w*16+lr)
  bf16x8 Qh[2], Ql[2];
  {
    const char* qh_t = (const char*)qhi + ((size_t)bb * NT + (size_t)qt * QT) * 128;
    const char* ql_t = (const char*)qlo + ((size_t)bb * NT + (size_t)qt * QT) * 128;
    int row = w * 16 + lr;
#pragma unroll
    for (int dc = 0; dc < 2; ++dc) {
      Qh[dc] = *(const bf16x8*)(qh_t + row * 128 + dc * 64 + lg * 16);
      Ql[dc] = *(const bf16x8*)(ql_t + row * 128 + dc * 64 + lg * 16);
    }
  }

  // --- stage tile `it` into buffer bufp via global_load_lds, pre-swizzled src.
  // Each wave covers chunks 2w,2w+1 of each 16KB array (6 loads/thread).
#define STAGE_TILE(bufp_, it_)                                                 \
  do {                                                                         \
    const char* kh_t = kh_base + (size_t)(it_) * KT * 128;                     \
    const char* kl_t = kl_base + (size_t)(it_) * KT * 128;                     \
    const char* v_tb = v_base + (size_t)(it_) * 256;                           \
    _Pragma("unroll")                                                          \
    for (int j = 0; j < 2; ++j) {                                              \
      int ch = 2 * w + j;                                                      \
      int d = ch * 1024 + l * 16;                                              \
      int swk = d ^ (((d >> 7) & 7) << 4);                                     \
      GLD_LDS16(kh_t + swk, (bufp_) + ch * 1024);                              \
      GLD_LDS16(kl_t + swk, (bufp_) + 16384 + ch * 1024);                      \
      int o = d >> 8;                                                          \
      int swv = (d ^ ((o & 7) << 4)) & 255;                                    \
      GLD_LDS16(v_tb + (size_t)o * 4096 + swv, (bufp_) + 32768 + ch * 1024);   \
    }                                                                          \
  } while (0)

  // prologue: stage tile 0 into buf 0
  STAGE_TILE(smem, 0);
  asm volatile("s_waitcnt vmcnt(0)" ::: "memory");
  __builtin_amdgcn_s_barrier();
  asm volatile("" ::: "memory");

  f32x4 O[4];
#pragma unroll
  for (int nb = 0; nb < 4; ++nb) O[nb] = {0.f, 0.f, 0.f, 0.f};
  float mrun = -1e30f;
  float lrun = 0.f;

  for (int it = 0; it < NT / KT; ++it) {
    const int c = it & 1;
    char* cb = smem + c * BUF;
    // issue next tile's loads into the other buffer (fly during compute)
    if (it + 1 < NT / KT) STAGE_TILE(smem + (1 - c) * BUF, it + 1);

    // --- S^T[key][qrow] = K · Q^T, 3-term hi/lo split
    f32x4 S[8];
    __builtin_amdgcn_s_setprio(1);
#pragma unroll
    for (int kb = 0; kb < 8; ++kb) {
      int krow = kb * 16 + lr;
      bf16x8 Ah[2], Al[2];
#pragma unroll
      for (int dc = 0; dc < 2; ++dc) {
        int byteoff = (krow * 128 + (dc * 32 + lg * 8) * 2) ^ ((krow & 7) << 4);
        Ah[dc] = *(const bf16x8*)(cb + byteoff);
        Al[dc] = *(const bf16x8*)(cb + 16384 + byteoff);
      }
      f32x4 a = {0.f, 0.f, 0.f, 0.f};
#pragma unroll
      for (int dc = 0; dc < 2; ++dc) {
        a = __builtin_amdgcn_mfma_f32_16x16x32_bf16(Ah[dc], Qh[dc], a, 0, 0, 0);
        a = __builtin_amdgcn_mfma_f32_16x16x32_bf16(Al[dc], Qh[dc], a, 0, 0, 0);
        a = __builtin_amdgcn_mfma_f32_16x16x32_bf16(Ah[dc], Ql[dc], a, 0, 0, 0);
      }
      S[kb] = a;
    }
    __builtin_amdgcn_s_setprio(0);

    // --- online softmax; stats at lane (l&15)=qrow
    float mt = -1e30f;
#pragma unroll
    for (int kb = 0; kb < 8; ++kb)
#pragma unroll
      for (int r = 0; r < 4; ++r) mt = fmaxf(mt, S[kb][r]);
    mt = fmaxf(mt, __shfl_xor(mt, 16));
    mt = fmaxf(mt, __shfl_xor(mt, 32));
    float mnew = fmaxf(mrun, mt);
    float alpha = __ocml_exp2_f32((mrun - mnew) * SC_LOG2E);
    mrun = mnew;
    float msS = mnew * SC_LOG2E;
    float ts = 0.f;
#pragma unroll
    for (int kb = 0; kb < 8; ++kb) {
      float p0 = __ocml_exp2_f32(fmaf(S[kb][0], SC_LOG2E, -msS));
      float p1 = __ocml_exp2_f32(fmaf(S[kb][1], SC_LOG2E, -msS));
      float p2 = __ocml_exp2_f32(fmaf(S[kb][2], SC_LOG2E, -msS));
      float p3 = __ocml_exp2_f32(fmaf(S[kb][3], SC_LOG2E, -msS));
      ts += (p0 + p1) + (p2 + p3);
      uint2 pk;
      pk.x = (uint32_t)f2bf(p0) | ((uint32_t)f2bf(p1) << 16);
      pk.y = (uint32_t)f2bf(p2) | ((uint32_t)f2bf(p3) << 16);
      int byteoff = (lr * 256 + kb * 32 + lg * 8) ^ ((lr & 7) << 4);
      *(uint2*)(smem + PB + w * 4096 + byteoff) = pk;
    }
    ts += __shfl_xor(ts, 16);
    ts += __shfl_xor(ts, 32);
    lrun = lrun * alpha + ts;
    // rescale O (O rows = lg*4+r; alpha lives at lane with (lane&15)=row)
    float ar[4];
#pragma unroll
    for (int r = 0; r < 4; ++r) ar[r] = __shfl(alpha, (l & 48) + lg * 4 + r);
#pragma unroll
    for (int nb = 0; nb < 4; ++nb)
#pragma unroll
      for (int r = 0; r < 4; ++r) O[nb][r] *= ar[r];

    // --- O += P · V   (A = P[qrow][key], B = V^T[d][key])
    __builtin_amdgcn_s_setprio(1);
#pragma unroll
    for (int kc = 0; kc < 4; ++kc) {
      bf16x8 Ap;
      {
        int byteoff = (lr * 256 + kc * 64 + lg * 16) ^ ((lr & 7) << 4);
        Ap = *(const bf16x8*)(smem + PB + w * 4096 + byteoff);
      }
      bf16x8 Bv[4];
#pragma unroll
      for (int nb = 0; nb < 4; ++nb) {
        int drow = nb * 16 + lr;
        int byteoff = (drow * 256 + kc * 64 + lg * 16) ^ ((drow & 7) << 4);
        Bv[nb] = *(const bf16x8*)(cb + 32768 + byteoff);
      }
#pragma unroll
      for (int nb = 0; nb < 4; ++nb)
        O[nb] = __builtin_amdgcn_mfma_f32_16x16x32_bf16(Ap, Bv[nb], O[nb], 0, 0, 0);
    }
    __builtin_amdgcn_s_setprio(0);

    // tail: drain next tile's loads (flew during compute), then publish
    asm volatile("s_waitcnt vmcnt(0)" ::: "memory");
    __builtin_amdgcn_s_barrier();
    asm volatile("" ::: "memory");
    __builtin_amdgcn_sched_barrier(0);
  }

  // epilogue: O / l
  {
    float inv = 1.0f / lrun;
    float ir[4];
#pragma unroll
    for (int r = 0; r < 4; ++r) ir[r] = __shfl(inv, (l & 48) + lg * 4 + r);
#pragma unroll
    for (int nb = 0; nb < 4; ++nb) {
      int d = nb * 16 + lr;
#pragma unroll
      for (int r = 0; r < 4; ++r) {
        int t = qt * QT + w * 16 + lg * 4 + r;
        out[((size_t)bb * NT + t) * 64 + d] = O[nb][r] * ir[r];
      }
    }
  }
#undef STAGE_TILE
}

extern "C" void kernel_launch(void* const* d_in, const int* in_sizes, int n_in,
                              void* d_out, int out_size, void* d_ws, size_t ws_size,
                              hipStream_t stream) {
  const float* x  = (const float*)d_in[0];
  const float* Wk = (const float*)d_in[1];
  const float* bk = (const float*)d_in[2];
  const float* Wq = (const float*)d_in[3];
  const float* bq = (const float*)d_in[4];
  const float* Wv = (const float*)d_in[5];
  const float* bv = (const float*)d_in[6];
  float* out = (float*)d_out;

  const size_t NE = (size_t)NBATCH * NT * 64;
  unsigned short* ws = (unsigned short*)d_ws;
  unsigned short* khi = ws;
  unsigned short* klo = ws + NE;
  unsigned short* qhi = ws + 2 * NE;
  unsigned short* qlo = ws + 3 * NE;
  unsigned short* vt  = ws + 4 * NE;

  proj_kernel<<<dim3((NBATCH * NT) / 64), dim3(256), 0, stream>>>(
      x, Wk, bk, Wq, bq, Wv, bv, khi, klo, qhi, qlo, vt);
  attn_kernel<<<dim3(NBATCH * (NT / QT)), dim3(512), 0, stream>>>(
      khi, klo, qhi, qlo, vt, out);
}

// Round 4
// 78.046 us; speedup vs baseline: 1.7523x; 1.0244x over previous
//
#include <hip/hip_runtime.h>
#include <hip/hip_bf16.h>
#include <stdint.h>

#define NBATCH 16
#define NT 2048
#define NC 64
#define QT 128
#define KT 128
#define SC_LOG2E 11.5415603f  // 8 * log2(e)

typedef __bf16 bf16x8 __attribute__((ext_vector_type(8)));
typedef float f32x4 __attribute__((ext_vector_type(4)));
typedef float f32x16 __attribute__((ext_vector_type(16)));

#define Z16 {0.f,0.f,0.f,0.f,0.f,0.f,0.f,0.f,0.f,0.f,0.f,0.f,0.f,0.f,0.f,0.f}

extern "C" __device__ float __ocml_exp2_f32(float);

static __device__ __forceinline__ unsigned short f2bf(float f) {
  __bf16 h = (__bf16)f;  // hardware RTNE convert
  union { __bf16 h; unsigned short u; } a; a.h = h; return a.u;
}
static __device__ __forceinline__ float bf2f(unsigned short h) {
  union { uint32_t u; float f; } a; a.u = ((uint32_t)h) << 16;
  return a.f;
}

#define GLD_LDS16(gsrc, ldst)                                                  \
  __builtin_amdgcn_global_load_lds(                                            \
      (const __attribute__((address_space(1))) void*)(gsrc),                   \
      (__attribute__((address_space(3))) void*)(ldst), 16, 0, 0)

// ---------------------------------------------------------------------------
// Kernel 1: q,k,v projections. 64 rows per block. (unchanged — known good)
// Outputs: khi/klo/qhi/qlo as [B*T][64] bf16 (hi/lo split), vt as [B][64][T].
// ---------------------------------------------------------------------------
__global__ __launch_bounds__(256, 2) void proj_kernel(
    const float* __restrict__ x,
    const float* __restrict__ Wk, const float* __restrict__ bk,
    const float* __restrict__ Wq, const float* __restrict__ bq,
    const float* __restrict__ Wv, const float* __restrict__ bv,
    unsigned short* __restrict__ khi, unsigned short* __restrict__ klo,
    unsigned short* __restrict__ qhi, unsigned short* __restrict__ qlo,
    unsigned short* __restrict__ vt)
{
  __shared__ __align__(16) char smem[65536];
  const int XH = 0, XL = 8192, WTH = 16384, WTL = 40960, VTB = 0; // VTB aliases XH
  const int tid = (int)threadIdx.x;
  const int l = tid & 63, w = tid >> 6;
  const int lr = l & 15, lg = l >> 4;
  const int blk = (int)blockIdx.x;
  const int rowbase = blk * 64;
  const int bb = blk >> 5;          // 32 blocks per batch

  for (int c = tid; c < 1024; c += 256) {
    int row = c >> 4, d0 = (c & 15) * 4;
    const float4 xv = *(const float4*)(x + (size_t)(rowbase + row) * NC + d0);
    unsigned short h0 = f2bf(xv.x), h1 = f2bf(xv.y), h2 = f2bf(xv.z), h3 = f2bf(xv.w);
    unsigned short m0 = f2bf(xv.x - bf2f(h0)), m1 = f2bf(xv.y - bf2f(h1));
    unsigned short m2 = f2bf(xv.z - bf2f(h2)), m3 = f2bf(xv.w - bf2f(h3));
    uint2 ph, pl;
    ph.x = (uint32_t)h0 | ((uint32_t)h1 << 16); ph.y = (uint32_t)h2 | ((uint32_t)h3 << 16);
    pl.x = (uint32_t)m0 | ((uint32_t)m1 << 16); pl.y = (uint32_t)m2 | ((uint32_t)m3 << 16);
    int byteoff = (row * 128 + d0 * 2) ^ ((row & 7) << 4);
    *(uint2*)(smem + XH + byteoff) = ph;
    *(uint2*)(smem + XL + byteoff) = pl;
  }
  for (int cw = tid; cw < 3072; cw += 256) {
    int og = cw >> 4, c0 = (cw & 15) * 4;
    const float* Wm = (og < 64) ? Wk : (og < 128 ? Wq : Wv);
    int o = og & 63;
    float w0 = Wm[(size_t)(c0 + 0) * 64 + o];
    float w1 = Wm[(size_t)(c0 + 1) * 64 + o];
    float w2 = Wm[(size_t)(c0 + 2) * 64 + o];
    float w3 = Wm[(size_t)(c0 + 3) * 64 + o];
    unsigned short h0 = f2bf(w0), h1 = f2bf(w1), h2 = f2bf(w2), h3 = f2bf(w3);
    unsigned short m0 = f2bf(w0 - bf2f(h0)), m1 = f2bf(w1 - bf2f(h1));
    unsigned short m2 = f2bf(w2 - bf2f(h2)), m3 = f2bf(w3 - bf2f(h3));
    uint2 ph, pl;
    ph.x = (uint32_t)h0 | ((uint32_t)h1 << 16); ph.y = (uint32_t)h2 | ((uint32_t)h3 << 16);
    pl.x = (uint32_t)m0 | ((uint32_t)m1 << 16); pl.y = (uint32_t)m2 | ((uint32_t)m3 << 16);
    int byteoff = (og * 128 + c0 * 2) ^ ((og & 7) << 4);
    *(uint2*)(smem + WTH + byteoff) = ph;
    *(uint2*)(smem + WTL + byteoff) = pl;
  }
  __syncthreads();

  bf16x8 Ah[2], Al[2];
  {
    int row = w * 16 + lr;
#pragma unroll
    for (int dc = 0; dc < 2; ++dc) {
      int byteoff = (row * 128 + (dc * 32 + lg * 8) * 2) ^ ((row & 7) << 4);
      Ah[dc] = *(const bf16x8*)(smem + XH + byteoff);
      Al[dc] = *(const bf16x8*)(smem + XL + byteoff);
    }
  }
  f32x4 acc[12];
#pragma unroll
  for (int nb = 0; nb < 12; ++nb) {
    f32x4 a = {0.f, 0.f, 0.f, 0.f};
    int og = nb * 16 + lr;
#pragma unroll
    for (int dc = 0; dc < 2; ++dc) {
      int byteoff = (og * 128 + (dc * 32 + lg * 8) * 2) ^ ((og & 7) << 4);
      bf16x8 bh = *(const bf16x8*)(smem + WTH + byteoff);
      bf16x8 bl = *(const bf16x8*)(smem + WTL + byteoff);
      a = __builtin_amdgcn_mfma_f32_16x16x32_bf16(Ah[dc], bh, a, 0, 0, 0);
      a = __builtin_amdgcn_mfma_f32_16x16x32_bf16(Al[dc], bh, a, 0, 0, 0);
      a = __builtin_amdgcn_mfma_f32_16x16x32_bf16(Ah[dc], bl, a, 0, 0, 0);
    }
    acc[nb] = a;
  }
  __syncthreads();  // done reading XH/XL; VTB may now alias

#pragma unroll
  for (int nb = 0; nb < 12; ++nb) {
    int og = nb * 16 + lr;
    const float* bp = (og < 64) ? bk : (og < 128 ? bq : bv);
    float bias = bp[og & 63];
#pragma unroll
    for (int r = 0; r < 4; ++r) {
      float val = acc[nb][r] + bias;
      int tloc = w * 16 + lg * 4 + r;
      size_t gt = (size_t)(rowbase + tloc);
      if (og < 64) {
        unsigned short h = f2bf(val);
        khi[gt * 64 + og] = h;
        klo[gt * 64 + og] = f2bf(val - bf2f(h));
      } else if (og < 128) {
        unsigned short h = f2bf(val);
        qhi[gt * 64 + (og - 64)] = h;
        qlo[gt * 64 + (og - 64)] = f2bf(val - bf2f(h));
      } else {
        int o = og - 128;
        int byteoff = (o * 128 + tloc * 2) ^ ((o & 7) << 4);
        *(unsigned short*)(smem + VTB + byteoff) = f2bf(val);
      }
    }
  }
  __syncthreads();
  for (int cc = tid; cc < 512; cc += 256) {
    int o = cc >> 3, t0 = (cc & 7) * 8;
    int byteoff = (o * 128 + t0 * 2) ^ ((o & 7) << 4);
    uint4 v = *(const uint4*)(smem + VTB + byteoff);
    *(uint4*)(vt + ((size_t)bb * 64 + o) * NT + (size_t)(blk & 31) * 64 + t0) = v;
  }
}

// ---------------------------------------------------------------------------
// Kernel 2: flash attention, 32x32 MFMA split-K structure.
// 8 waves = 4 q-groups (32 rows) x 2 key-halves (64 keys). Per-wave online
// softmax over its key half; in-register P via cvt_pk + shfl_xor(32);
// O^T = V^T · P^T keeps all stats lane-local. Epilogue merges key halves.
// ---------------------------------------------------------------------------
__global__ __launch_bounds__(512, 2) void attn_kernel(
    const unsigned short* __restrict__ khi, const unsigned short* __restrict__ klo,
    const unsigned short* __restrict__ qhi, const unsigned short* __restrict__ qlo,
    const unsigned short* __restrict__ vt,
    float* __restrict__ out)
{
  __shared__ __align__(16) char smem[98304];
  const int BUF = 49152;   // per-buffer: KHI 16K | KLO 16K | VT 16K
  const int MLB = 32768;   // epilogue: m/l exchange (aliases buf0)
  const int FINAL = 36864; // epilogue: final [128 q][64 d] f32 (aliases bufs)
  const int tid = (int)threadIdx.x;
  const int l = tid & 63, w = tid >> 6;     // w in 0..7
  const int lq = l & 31;                    // q-lane (S cols) / d-lane (O^T cols... rows)
  const bool hi = (l >= 32);
  const int hioff = hi ? 16 : 0;
  const int r = w & 3;                      // q-group: rows 32r..32r+31
  const int cc = w >> 2;                    // key half: keys 64cc..64cc+63
  // XCD-aware swizzle: 256 blocks -> 2 whole batches per XCD
  const int lb = ((int)(blockIdx.x & 7) << 5) | ((int)blockIdx.x >> 3);
  const int bb = lb >> 4;
  const int qt = lb & 15;

  const char* kh_base = (const char*)(khi + (size_t)bb * NT * 64);
  const char* kl_base = (const char*)(klo + (size_t)bb * NT * 64);
  const char* v_base  = (const char*)(vt + (size_t)bb * 64 * NT);

#define STAGE_TILE(bufp_, it_)                                                 \
  do {                                                                         \
    const char* kh_t = kh_base + (size_t)(it_) * KT * 128;                     \
    const char* kl_t = kl_base + (size_t)(it_) * KT * 128;                     \
    const char* v_tb = v_base + (size_t)(it_) * 256;                           \
    _Pragma("unroll")                                                          \
    for (int j = 0; j < 2; ++j) {                                              \
      int ch = 2 * w + j;                                                      \
      int d = ch * 1024 + l * 16;                                              \
      int swk = d ^ (((d >> 7) & 7) << 4);                                     \
      GLD_LDS16(kh_t + swk, (bufp_) + ch * 1024);                              \
      GLD_LDS16(kl_t + swk, (bufp_) + 16384 + ch * 1024);                      \
      int o = d >> 8;                                                          \
      int swv = (d ^ ((o & 7) << 4)) & 255;                                    \
      GLD_LDS16(v_tb + (size_t)o * 4096 + swv, (bufp_) + 32768 + ch * 1024);   \
    }                                                                          \
  } while (0)

  // prologue: stage tile 0, load Q fragments (rows 32r..32r+31, B-operand)
  STAGE_TILE(smem, 0);
  bf16x8 Qh[4], Ql[4];
  {
    const char* qh_t = (const char*)qhi + ((size_t)bb * NT + (size_t)qt * QT) * 128;
    const char* ql_t = (const char*)qlo + ((size_t)bb * NT + (size_t)qt * QT) * 128;
    int qrow = r * 32 + lq;
#pragma unroll
    for (int dc = 0; dc < 4; ++dc) {
      Qh[dc] = *(const bf16x8*)(qh_t + qrow * 128 + dc * 32 + hioff);
      Ql[dc] = *(const bf16x8*)(ql_t + qrow * 128 + dc * 32 + hioff);
    }
  }
  asm volatile("s_waitcnt vmcnt(0)" ::: "memory");
  __builtin_amdgcn_s_barrier();
  asm volatile("" ::: "memory");

  f32x16 O0 = Z16, O1 = Z16;
  float mrun = -1e30f, lrun = 0.f;
  const int swr = (lq & 7) << 4;

  for (int it = 0; it < NT / KT; ++it) {
    char* cb = smem + (it & 1) * BUF;
    if (it + 1 < NT / KT) STAGE_TILE(smem + ((it + 1) & 1) * BUF, it + 1);

    // --- S^T[key][q] = K · Q^T (3-term hi/lo), keys = this wave's 64-half
    f32x16 S0 = Z16, S1 = Z16;
    __builtin_amdgcn_s_setprio(1);
#pragma unroll
    for (int dc = 0; dc < 4; ++dc) {
      int row0 = cc * 64 + lq;
      int row1 = row0 + 32;
      int cchunk = (32 * dc + hioff) ^ swr;   // (row&7)==(lq&7) for both rows
      bf16x8 Ah0 = *(const bf16x8*)(cb + row0 * 128 + cchunk);
      bf16x8 Al0 = *(const bf16x8*)(cb + 16384 + row0 * 128 + cchunk);
      bf16x8 Ah1 = *(const bf16x8*)(cb + row1 * 128 + cchunk);
      bf16x8 Al1 = *(const bf16x8*)(cb + 16384 + row1 * 128 + cchunk);
      S0 = __builtin_amdgcn_mfma_f32_32x32x16_bf16(Ah0, Qh[dc], S0, 0, 0, 0);
      S1 = __builtin_amdgcn_mfma_f32_32x32x16_bf16(Ah1, Qh[dc], S1, 0, 0, 0);
      S0 = __builtin_amdgcn_mfma_f32_32x32x16_bf16(Al0, Qh[dc], S0, 0, 0, 0);
      S1 = __builtin_amdgcn_mfma_f32_32x32x16_bf16(Al1, Qh[dc], S1, 0, 0, 0);
      S0 = __builtin_amdgcn_mfma_f32_32x32x16_bf16(Ah0, Ql[dc], S0, 0, 0, 0);
      S1 = __builtin_amdgcn_mfma_f32_32x32x16_bf16(Ah1, Ql[dc], S1, 0, 0, 0);
    }
    __builtin_amdgcn_s_setprio(0);

    // --- online softmax (per-lane q = r*32+lq, keys split with partner lane)
    float pmax = S0[0];
#pragma unroll
    for (int i = 1; i < 16; ++i) pmax = fmaxf(pmax, S0[i]);
#pragma unroll
    for (int i = 0; i < 16; ++i) pmax = fmaxf(pmax, S1[i]);
    pmax = fmaxf(pmax, __shfl_xor(pmax, 32));
    if (__any(pmax > mrun + 1.0f)) {        // T13 defer-max (THR=1 in S units)
      float mnew = fmaxf(mrun, pmax);
      float alpha = __ocml_exp2_f32((mrun - mnew) * SC_LOG2E);
      O0 *= alpha; O1 *= alpha; lrun *= alpha; mrun = mnew;
    }
    float mk = mrun * SC_LOG2E;
    float p0[16], p1[16];
    float ts = 0.f;
#pragma unroll
    for (int i = 0; i < 16; ++i) {
      p0[i] = __ocml_exp2_f32(fmaf(S0[i], SC_LOG2E, -mk));
      ts += p0[i];
    }
#pragma unroll
    for (int i = 0; i < 16; ++i) {
      p1[i] = __ocml_exp2_f32(fmaf(S1[i], SC_LOG2E, -mk));
      ts += p1[i];
    }
    ts += __shfl_xor(ts, 32);
    lrun += ts;

    // --- O^T += V^T · P^T  (A = V^T frag from LDS, B = P^T built in-register)
#define PV_CHUNK(kc_, PARR)                                                    \
    {                                                                          \
      const int b_ = 8 * ((kc_) & 1);                                          \
      uint32_t X0, X1, Y0, Y1;                                                 \
      asm("v_cvt_pk_bf16_f32 %0, %1, %2" : "=v"(X0) : "v"(PARR[b_+0]), "v"(PARR[b_+1])); \
      asm("v_cvt_pk_bf16_f32 %0, %1, %2" : "=v"(X1) : "v"(PARR[b_+2]), "v"(PARR[b_+3])); \
      asm("v_cvt_pk_bf16_f32 %0, %1, %2" : "=v"(Y0) : "v"(PARR[b_+4]), "v"(PARR[b_+5])); \
      asm("v_cvt_pk_bf16_f32 %0, %1, %2" : "=v"(Y1) : "v"(PARR[b_+6]), "v"(PARR[b_+7])); \
      uint32_t s0 = hi ? X0 : Y0, s1 = hi ? X1 : Y1;                           \
      uint32_t r0 = (uint32_t)__shfl_xor((int)s0, 32);                         \
      uint32_t r1 = (uint32_t)__shfl_xor((int)s1, 32);                         \
      union { uint32_t u[4]; bf16x8 v; } cvb;                                  \
      cvb.u[0] = hi ? r0 : X0; cvb.u[1] = hi ? r1 : X1;                        \
      cvb.u[2] = hi ? Y0 : r0; cvb.u[3] = hi ? Y1 : r1;                        \
      bf16x8 Bp = cvb.v;                                                       \
      int vcol = 128 * cc + 32 * (kc_) + hioff;                                \
      {                                                                        \
        int drow = lq;                                                         \
        bf16x8 Av = *(const bf16x8*)(cb + 32768 + drow * 256 + (vcol ^ swr));  \
        O0 = __builtin_amdgcn_mfma_f32_32x32x16_bf16(Av, Bp, O0, 0, 0, 0);     \
      }                                                                        \
      {                                                                        \
        int drow = 32 + lq;                                                    \
        bf16x8 Av = *(const bf16x8*)(cb + 32768 + drow * 256 + (vcol ^ swr));  \
        O1 = __builtin_amdgcn_mfma_f32_32x32x16_bf16(Av, Bp, O1, 0, 0, 0);     \
      }                                                                        \
    }
    __builtin_amdgcn_s_setprio(1);
    PV_CHUNK(0, p0)
    PV_CHUNK(1, p0)
    PV_CHUNK(2, p1)
    PV_CHUNK(3, p1)
    __builtin_amdgcn_s_setprio(0);
#undef PV_CHUNK

    // tail: drain next tile's loads (flew during compute), then publish
    asm volatile("s_waitcnt vmcnt(0)" ::: "memory");
    __builtin_amdgcn_s_barrier();
    asm volatile("" ::: "memory");
    __builtin_amdgcn_sched_barrier(0);
  }

  // --- epilogue: merge key halves (cc=0 <- cc=1), transpose, write out
  const int lsw = (l & 7) << 4;
  if (cc == 1) {
    char* ddst = smem + r * 8192 + l * 128;
#pragma unroll
    for (int g = 0; g < 4; ++g) {
      f32x4 t0, t1;
#pragma unroll
      for (int j = 0; j < 4; ++j) { t0[j] = O0[4 * g + j]; t1[j] = O1[4 * g + j]; }
      *(f32x4*)(ddst + ((g * 16) ^ lsw)) = t0;
      *(f32x4*)(ddst + ((64 + g * 16) ^ lsw)) = t1;
    }
    *(float*)(smem + MLB + r * 256 + lq * 8) = mrun;
    *(float*)(smem + MLB + r * 256 + lq * 8 + 4) = lrun;
  }
  __syncthreads();
  if (cc == 0) {
    float m1 = *(const float*)(smem + MLB + r * 256 + lq * 8);
    float l1 = *(const float*)(smem + MLB + r * 256 + lq * 8 + 4);
    float M = fmaxf(mrun, m1);
    float a0 = __ocml_exp2_f32((mrun - M) * SC_LOG2E);
    float a1 = __ocml_exp2_f32((m1 - M) * SC_LOG2E);
    float Lt = lrun * a0 + l1 * a1;
    float f0 = a0 / Lt, f1 = a1 / Lt;
    const char* dsrc = smem + r * 8192 + l * 128;
    int qloc = 32 * r + lq;
    int qsw = (qloc & 7) << 4;
#pragma unroll
    for (int g = 0; g < 4; ++g) {
      f32x4 o1a = *(const f32x4*)(dsrc + ((g * 16) ^ lsw));
      f32x4 o1b = *(const f32x4*)(dsrc + ((64 + g * 16) ^ lsw));
#pragma unroll
      for (int j = 0; j < 4; ++j) {
        int dp = j + 8 * g + (hi ? 4 : 0);
        float ofa = O0[4 * g + j] * f0 + o1a[j] * f1;
        float ofb = O1[4 * g + j] * f0 + o1b[j] * f1;
        *(float*)(smem + FINAL + qloc * 256 + ((dp * 4) ^ qsw)) = ofa;
        *(float*)(smem + FINAL + qloc * 256 + (((128 + dp * 4)) ^ qsw)) = ofb;
      }
    }
  }
  __syncthreads();
#pragma unroll
  for (int j = 0; j < 4; ++j) {
    int lin = (tid + j * 512) * 16;
    int row = lin >> 8, col = lin & 255;
    uint4 vv = *(const uint4*)(smem + FINAL + row * 256 + (col ^ ((row & 7) << 4)));
    *(uint4*)((char*)out + ((size_t)bb * NT + (size_t)qt * QT + row) * 256 + col) = vv;
  }
#undef STAGE_TILE
}

extern "C" void kernel_launch(void* const* d_in, const int* in_sizes, int n_in,
                              void* d_out, int out_size, void* d_ws, size_t ws_size,
                              hipStream_t stream) {
  const float* x  = (const float*)d_in[0];
  const float* Wk = (const float*)d_in[1];
  const float* bk = (const float*)d_in[2];
  const float* Wq = (const float*)d_in[3];
  const float* bq = (const float*)d_in[4];
  const float* Wv = (const float*)d_in[5];
  const float* bv = (const float*)d_in[6];
  float* out = (float*)d_out;

  const size_t NE = (size_t)NBATCH * NT * 64;
  unsigned short* ws = (unsigned short*)d_ws;
  unsigned short* khi = ws;
  unsigned short* klo = ws + NE;
  unsigned short* qhi = ws + 2 * NE;
  unsigned short* qlo = ws + 3 * NE;
  unsigned short* vt  = ws + 4 * NE;

  proj_kernel<<<dim3((NBATCH * NT) / 64), dim3(256), 0, stream>>>(
      x, Wk, bk, Wq, bq, Wv, bv, khi, klo, qhi, qlo, vt);
  attn_kernel<<<dim3(NBATCH * (NT / QT)), dim3(512), 0, stream>>>(
      khi, klo, qhi, qlo, vt, out);
}

// Round 5
// 77.643 us; speedup vs baseline: 1.7614x; 1.0052x over previous
//
#include <hip/hip_runtime.h>
#include <hip/hip_bf16.h>
#include <stdint.h>

#define NBATCH 16
#define NT 2048
#define NC 64
#define QT 128
#define KT 128
#define SC_LOG2E 11.5415603f  // 8 * log2(e)

typedef __bf16 bf16x8 __attribute__((ext_vector_type(8)));
typedef float f32x4 __attribute__((ext_vector_type(4)));
typedef float f32x16 __attribute__((ext_vector_type(16)));

#define Z16 {0.f,0.f,0.f,0.f,0.f,0.f,0.f,0.f,0.f,0.f,0.f,0.f,0.f,0.f,0.f,0.f}

extern "C" __device__ float __ocml_exp2_f32(float);

static __device__ __forceinline__ unsigned short f2bf(float f) {
  __bf16 h = (__bf16)f;  // hardware RTNE convert
  union { __bf16 h; unsigned short u; } a; a.h = h; return a.u;
}
static __device__ __forceinline__ float bf2f(unsigned short h) {
  union { uint32_t u; float f; } a; a.u = ((uint32_t)h) << 16;
  return a.f;
}

#define GLD_LDS16(gsrc, ldst)                                                  \
  __builtin_amdgcn_global_load_lds(                                            \
      (const __attribute__((address_space(1))) void*)(gsrc),                   \
      (__attribute__((address_space(3))) void*)(ldst), 16, 0, 0)

// ---------------------------------------------------------------------------
// Kernel 1: q,k,v projections. 64 rows per block.
// MFMA with A=W^T (og in reg dim) so k/q stores pack into ushort4.
// Q is pre-scaled by 8*log2(e) so attn softmax is exp2-direct.
// Outputs: khi/klo/qhi/qlo as [B*T][64] bf16 (hi/lo split), vt as [B][64][T].
// ---------------------------------------------------------------------------
__global__ __launch_bounds__(256, 2) void proj_kernel(
    const float* __restrict__ x,
    const float* __restrict__ Wk, const float* __restrict__ bk,
    const float* __restrict__ Wq, const float* __restrict__ bq,
    const float* __restrict__ Wv, const float* __restrict__ bv,
    unsigned short* __restrict__ khi, unsigned short* __restrict__ klo,
    unsigned short* __restrict__ qhi, unsigned short* __restrict__ qlo,
    unsigned short* __restrict__ vt)
{
  __shared__ __align__(16) char smem[65536];
  const int XH = 0, XL = 8192, WTH = 16384, WTL = 40960, VTB = 0; // VTB aliases XH
  const int tid = (int)threadIdx.x;
  const int l = tid & 63, w = tid >> 6;
  const int lr = l & 15, lg = l >> 4;
  const int blk = (int)blockIdx.x;
  const int rowbase = blk * 64;
  const int bb = blk >> 5;          // 32 blocks per batch

  // stage x tile (64x64 f32) as hi/lo bf16, swizzled
  for (int c = tid; c < 1024; c += 256) {
    int row = c >> 4, d0 = (c & 15) * 4;
    const float4 xv = *(const float4*)(x + (size_t)(rowbase + row) * NC + d0);
    unsigned short h0 = f2bf(xv.x), h1 = f2bf(xv.y), h2 = f2bf(xv.z), h3 = f2bf(xv.w);
    unsigned short m0 = f2bf(xv.x - bf2f(h0)), m1 = f2bf(xv.y - bf2f(h1));
    unsigned short m2 = f2bf(xv.z - bf2f(h2)), m3 = f2bf(xv.w - bf2f(h3));
    uint2 ph, pl;
    ph.x = (uint32_t)h0 | ((uint32_t)h1 << 16); ph.y = (uint32_t)h2 | ((uint32_t)h3 << 16);
    pl.x = (uint32_t)m0 | ((uint32_t)m1 << 16); pl.y = (uint32_t)m2 | ((uint32_t)m3 << 16);
    int byteoff = (row * 128 + d0 * 2) ^ ((row & 7) << 4);
    *(uint2*)(smem + XH + byteoff) = ph;
    *(uint2*)(smem + XL + byteoff) = pl;
  }
  // stage W^T (192 og-rows x 64 c-cols) as hi/lo bf16, swizzled
  for (int cw = tid; cw < 3072; cw += 256) {
    int og = cw >> 4, c0 = (cw & 15) * 4;
    const float* Wm = (og < 64) ? Wk : (og < 128 ? Wq : Wv);
    int o = og & 63;
    float w0 = Wm[(size_t)(c0 + 0) * 64 + o];
    float w1 = Wm[(size_t)(c0 + 1) * 64 + o];
    float w2 = Wm[(size_t)(c0 + 2) * 64 + o];
    float w3 = Wm[(size_t)(c0 + 3) * 64 + o];
    unsigned short h0 = f2bf(w0), h1 = f2bf(w1), h2 = f2bf(w2), h3 = f2bf(w3);
    unsigned short m0 = f2bf(w0 - bf2f(h0)), m1 = f2bf(w1 - bf2f(h1));
    unsigned short m2 = f2bf(w2 - bf2f(h2)), m3 = f2bf(w3 - bf2f(h3));
    uint2 ph, pl;
    ph.x = (uint32_t)h0 | ((uint32_t)h1 << 16); ph.y = (uint32_t)h2 | ((uint32_t)h3 << 16);
    pl.x = (uint32_t)m0 | ((uint32_t)m1 << 16); pl.y = (uint32_t)m2 | ((uint32_t)m3 << 16);
    int byteoff = (og * 128 + c0 * 2) ^ ((og & 7) << 4);
    *(uint2*)(smem + WTH + byteoff) = ph;
    *(uint2*)(smem + WTL + byteoff) = pl;
  }
  __syncthreads();

  // x B-frags for this wave's 16 rows (t = w*16 + lr)
  bf16x8 xh[2], xl[2];
  {
    int row = w * 16 + lr;
#pragma unroll
    for (int dc = 0; dc < 2; ++dc) {
      int byteoff = (row * 128 + (dc * 32 + lg * 8) * 2) ^ ((row & 7) << 4);
      xh[dc] = *(const bf16x8*)(smem + XH + byteoff);
      xl[dc] = *(const bf16x8*)(smem + XL + byteoff);
    }
  }
  // A = W^T (rows og -> C reg dim), B = x (rows t -> C lane dim)
  f32x4 acc[12];
#pragma unroll
  for (int nb = 0; nb < 12; ++nb) {
    f32x4 a = {0.f, 0.f, 0.f, 0.f};
    int og = nb * 16 + lr;
#pragma unroll
    for (int dc = 0; dc < 2; ++dc) {
      int byteoff = (og * 128 + (dc * 32 + lg * 8) * 2) ^ ((og & 7) << 4);
      bf16x8 bh = *(const bf16x8*)(smem + WTH + byteoff);
      bf16x8 bl = *(const bf16x8*)(smem + WTL + byteoff);
      a = __builtin_amdgcn_mfma_f32_16x16x32_bf16(bh, xh[dc], a, 0, 0, 0);
      a = __builtin_amdgcn_mfma_f32_16x16x32_bf16(bl, xh[dc], a, 0, 0, 0);
      a = __builtin_amdgcn_mfma_f32_16x16x32_bf16(bh, xl[dc], a, 0, 0, 0);
    }
    acc[nb] = a;
  }
  __syncthreads();  // done reading XH/XL; VTB may now alias

  // epilogue: lane holds t = w*16+lr, og = nb*16 + lg*4 + r (4 consecutive)
  const int tloc = w * 16 + lr;
  const size_t gt = (size_t)(rowbase + tloc);
#pragma unroll
  for (int nb = 0; nb < 12; ++nb) {
    int ogb = (nb & 3) * 16 + lg * 4;
    const float* bp = (nb < 4) ? bk : (nb < 8 ? bq : bv);
    float4 bias = *(const float4*)(bp + ogb);
    float v0 = acc[nb][0] + bias.x, v1 = acc[nb][1] + bias.y,
          v2 = acc[nb][2] + bias.z, v3 = acc[nb][3] + bias.w;
    if (nb < 8) {
      if (nb >= 4) { v0 *= SC_LOG2E; v1 *= SC_LOG2E; v2 *= SC_LOG2E; v3 *= SC_LOG2E; }
      ushort4 hv, lv;
      hv.x = f2bf(v0); lv.x = f2bf(v0 - bf2f(hv.x));
      hv.y = f2bf(v1); lv.y = f2bf(v1 - bf2f(hv.y));
      hv.z = f2bf(v2); lv.z = f2bf(v2 - bf2f(hv.z));
      hv.w = f2bf(v3); lv.w = f2bf(v3 - bf2f(hv.w));
      unsigned short* dH = (nb < 4) ? khi : qhi;
      unsigned short* dL = (nb < 4) ? klo : qlo;
      *(ushort4*)(dH + gt * 64 + ogb) = hv;
      *(ushort4*)(dL + gt * 64 + ogb) = lv;
    } else {
      // v: into LDS transpose buffer [o 64][t 64] bf16, swizzled
      float vs[4] = {v0, v1, v2, v3};
#pragma unroll
      for (int r = 0; r < 4; ++r) {
        int o = ogb + r;
        int byteoff = (o * 128 + tloc * 2) ^ ((o & 7) << 4);
        *(unsigned short*)(smem + VTB + byteoff) = f2bf(vs[r]);
      }
    }
  }
  __syncthreads();
  // copy v^T tile [64 o][64 t] to global [B][64][T]
  for (int cc = tid; cc < 512; cc += 256) {
    int o = cc >> 3, t0 = (cc & 7) * 8;
    int byteoff = (o * 128 + t0 * 2) ^ ((o & 7) << 4);
    uint4 v = *(const uint4*)(smem + VTB + byteoff);
    *(uint4*)(vt + ((size_t)bb * 64 + o) * NT + (size_t)(blk & 31) * 64 + t0) = v;
  }
}

// ---------------------------------------------------------------------------
// Kernel 2: flash attention. QT=128, KT=128, 1024 threads = 16 waves =
// 4 q-groups x 4 key-quarters (4-way split-K). 4 waves/SIMD occupancy.
// Per wave: 32q x 32keys via 32x32x16 MFMA; in-register P; tree-reduced
// softmax in log2 units (Q pre-scaled). 2-stage split-K merge epilogue.
// ---------------------------------------------------------------------------
__global__ __launch_bounds__(1024, 4) void attn_kernel(
    const unsigned short* __restrict__ khi, const unsigned short* __restrict__ klo,
    const unsigned short* __restrict__ qhi, const unsigned short* __restrict__ qlo,
    const unsigned short* __restrict__ vt,
    float* __restrict__ out)
{
  __shared__ __align__(16) char smem[98304];
  const int BUF = 49152;   // per-buffer: KHI 16K | KLO 16K | VT 16K
  const int MLB = 65536;   // epilogue m/l exchange (aliases buf space)
  const int tid = (int)threadIdx.x;
  const int l = tid & 63, w = tid >> 6;     // w in 0..15
  const int lq = l & 31;
  const bool hi = (l >= 32);
  const int hioff = hi ? 16 : 0;
  const int r = w & 3;                      // q-group: rows 32r..32r+31
  const int cc = w >> 2;                    // key quarter: keys 32cc..32cc+31
  // XCD-aware swizzle: 256 blocks -> 2 whole batches per XCD
  const int lb = ((int)(blockIdx.x & 7) << 5) | ((int)blockIdx.x >> 3);
  const int bb = lb >> 4;
  const int qt = lb & 15;

  const char* kh_base = (const char*)(khi + (size_t)bb * NT * 64);
  const char* kl_base = (const char*)(klo + (size_t)bb * NT * 64);
  const char* v_base  = (const char*)(vt + (size_t)bb * 64 * NT);

  // 48 1KB-chunks per tile; wave w stages chunk w of each of the 3 regions.
#define STAGE_TILE(bufp_, it_)                                                 \
  do {                                                                         \
    const char* kh_t = kh_base + (size_t)(it_) * 16384;                        \
    const char* kl_t = kl_base + (size_t)(it_) * 16384;                        \
    const char* v_tb = v_base + (size_t)(it_) * 256;                           \
    int d_ = w * 1024 + l * 16;                                                \
    int swk_ = d_ ^ (((d_ >> 7) & 7) << 4);                                    \
    GLD_LDS16(kh_t + swk_, (bufp_) + w * 1024);                                \
    GLD_LDS16(kl_t + swk_, (bufp_) + 16384 + w * 1024);                        \
    int o_ = d_ >> 8;                                                          \
    int swv_ = (d_ & 255) ^ ((o_ & 7) << 4);                                   \
    GLD_LDS16(v_tb + (size_t)o_ * 4096 + swv_, (bufp_) + 32768 + w * 1024);    \
  } while (0)

  // prologue: stage tile 0; load Q fragments (rows 32r..32r+31, B-operand)
  STAGE_TILE(smem, 0);
  bf16x8 Qh[4], Ql[4];
  {
    const char* qh_t = (const char*)qhi + ((size_t)bb * NT + (size_t)qt * QT) * 128;
    const char* ql_t = (const char*)qlo + ((size_t)bb * NT + (size_t)qt * QT) * 128;
    int qrow = r * 32 + lq;
#pragma unroll
    for (int dc = 0; dc < 4; ++dc) {
      Qh[dc] = *(const bf16x8*)(qh_t + qrow * 128 + dc * 32 + hioff);
      Ql[dc] = *(const bf16x8*)(ql_t + qrow * 128 + dc * 32 + hioff);
    }
  }
  asm volatile("s_waitcnt vmcnt(0)" ::: "memory");
  __builtin_amdgcn_s_barrier();
  asm volatile("" ::: "memory");

  f32x16 O0 = Z16, O1 = Z16;
  float mrun = -1e30f, lrun = 0.f;
  const int swr = (lq & 7) << 4;

  for (int it = 0; it < NT / KT; ++it) {
    char* cb = smem + (it & 1) * BUF;
    if (it + 1 < NT / KT) STAGE_TILE(smem + ((it + 1) & 1) * BUF, it + 1);

    // --- S^T[key][q] = K · Q^T (3-term hi/lo), keys = wave's 32-quarter
    f32x16 S = Z16;
    __builtin_amdgcn_s_setprio(1);
#pragma unroll
    for (int dc = 0; dc < 4; ++dc) {
      int krow = cc * 32 + lq;
      int cchunk = (dc * 32 + hioff) ^ swr;
      bf16x8 Ah = *(const bf16x8*)(cb + krow * 128 + cchunk);
      bf16x8 Al = *(const bf16x8*)(cb + 16384 + krow * 128 + cchunk);
      S = __builtin_amdgcn_mfma_f32_32x32x16_bf16(Ah, Qh[dc], S, 0, 0, 0);
      S = __builtin_amdgcn_mfma_f32_32x32x16_bf16(Al, Qh[dc], S, 0, 0, 0);
      S = __builtin_amdgcn_mfma_f32_32x32x16_bf16(Ah, Ql[dc], S, 0, 0, 0);
    }
    __builtin_amdgcn_s_setprio(0);

    // --- online softmax in log2 units; tree reductions
    float m01 = fmaxf(S[0], S[1]),   m23 = fmaxf(S[2], S[3]);
    float m45 = fmaxf(S[4], S[5]),   m67 = fmaxf(S[6], S[7]);
    float m89 = fmaxf(S[8], S[9]),   mab = fmaxf(S[10], S[11]);
    float mcd = fmaxf(S[12], S[13]), mef = fmaxf(S[14], S[15]);
    float pmax = fmaxf(fmaxf(fmaxf(m01, m23), fmaxf(m45, m67)),
                       fmaxf(fmaxf(m89, mab), fmaxf(mcd, mef)));
    pmax = fmaxf(pmax, __shfl_xor(pmax, 32));
    if (__any(pmax > mrun + 11.55f)) {      // defer-max (e^1 logit window)
      float mnew = fmaxf(mrun, pmax);
      float alpha = __ocml_exp2_f32(mrun - mnew);
      O0 *= alpha; O1 *= alpha; lrun *= alpha; mrun = mnew;
    }
    float p[16];
#pragma unroll
    for (int i = 0; i < 16; ++i) p[i] = __ocml_exp2_f32(S[i] - mrun);
    float s01 = p[0] + p[1],   s23 = p[2] + p[3];
    float s45 = p[4] + p[5],   s67 = p[6] + p[7];
    float s89 = p[8] + p[9],   sab = p[10] + p[11];
    float scd = p[12] + p[13], sef = p[14] + p[15];
    float ts = ((s01 + s23) + (s45 + s67)) + ((s89 + sab) + (scd + sef));
    ts += __shfl_xor(ts, 32);
    lrun += ts;

    // --- O^T += V^T · P^T  (A = V^T frag from LDS, B = P^T in-register)
#define PV_CHUNK(kc_)                                                          \
    {                                                                          \
      const int b_ = 8 * (kc_);                                                \
      uint32_t X0, X1, Y0, Y1;                                                 \
      asm("v_cvt_pk_bf16_f32 %0, %1, %2" : "=v"(X0) : "v"(p[b_+0]), "v"(p[b_+1])); \
      asm("v_cvt_pk_bf16_f32 %0, %1, %2" : "=v"(X1) : "v"(p[b_+2]), "v"(p[b_+3])); \
      asm("v_cvt_pk_bf16_f32 %0, %1, %2" : "=v"(Y0) : "v"(p[b_+4]), "v"(p[b_+5])); \
      asm("v_cvt_pk_bf16_f32 %0, %1, %2" : "=v"(Y1) : "v"(p[b_+6]), "v"(p[b_+7])); \
      uint32_t s0 = hi ? X0 : Y0, s1 = hi ? X1 : Y1;                           \
      uint32_t r0 = (uint32_t)__shfl_xor((int)s0, 32);                         \
      uint32_t r1 = (uint32_t)__shfl_xor((int)s1, 32);                         \
      union { uint32_t u[4]; bf16x8 v; } cvb;                                  \
      cvb.u[0] = hi ? r0 : X0; cvb.u[1] = hi ? r1 : X1;                        \
      cvb.u[2] = hi ? Y0 : r0; cvb.u[3] = hi ? Y1 : r1;                        \
      bf16x8 Bp = cvb.v;                                                       \
      int vcol = 64 * cc + 32 * (kc_) + hioff;                                 \
      {                                                                        \
        bf16x8 Av = *(const bf16x8*)(cb + 32768 + lq * 256 + (vcol ^ swr));    \
        O0 = __builtin_amdgcn_mfma_f32_32x32x16_bf16(Av, Bp, O0, 0, 0, 0);     \
      }                                                                        \
      {                                                                        \
        bf16x8 Av = *(const bf16x8*)(cb + 32768 + (32 + lq) * 256 + (vcol ^ swr)); \
        O1 = __builtin_amdgcn_mfma_f32_32x32x16_bf16(Av, Bp, O1, 0, 0, 0);     \
      }                                                                        \
    }
    __builtin_amdgcn_s_setprio(1);
    PV_CHUNK(0)
    PV_CHUNK(1)
    __builtin_amdgcn_s_setprio(0);
#undef PV_CHUNK

    // tail: drain next tile's loads (flew during compute), then publish
    asm volatile("s_waitcnt vmcnt(0)" ::: "memory");
    __builtin_amdgcn_s_barrier();
    asm volatile("" ::: "memory");
    __builtin_amdgcn_sched_barrier(0);
  }

  // --- epilogue: 2-stage 4-way split-K merge, then direct f32x4 stores
  const int lsw = (l & 7) << 4;
#define DUMP(idx_)                                                             \
  {                                                                            \
    char* dd = smem + (idx_) * 8192 + l * 128;                                 \
    _Pragma("unroll")                                                          \
    for (int g = 0; g < 4; ++g) {                                              \
      f32x4 t0, t1;                                                            \
      _Pragma("unroll")                                                        \
      for (int j = 0; j < 4; ++j) { t0[j] = O0[4*g+j]; t1[j] = O1[4*g+j]; }    \
      *(f32x4*)(dd + ((g * 16) ^ lsw)) = t0;                                   \
      *(f32x4*)(dd + ((64 + g * 16) ^ lsw)) = t1;                              \
    }                                                                          \
    *(float*)(smem + MLB + (idx_) * 256 + lq * 8) = mrun;                      \
    *(float*)(smem + MLB + (idx_) * 256 + lq * 8 + 4) = lrun;                  \
  }
#define MERGE(idx_)                                                            \
  {                                                                            \
    const char* ds = smem + (idx_) * 8192 + l * 128;                           \
    float m1 = *(const float*)(smem + MLB + (idx_) * 256 + lq * 8);            \
    float l1 = *(const float*)(smem + MLB + (idx_) * 256 + lq * 8 + 4);        \
    float M = fmaxf(mrun, m1);                                                 \
    float a0 = __ocml_exp2_f32(mrun - M);                                      \
    float a1 = __ocml_exp2_f32(m1 - M);                                        \
    lrun = lrun * a0 + l1 * a1;                                                \
    mrun = M;                                                                  \
    _Pragma("unroll")                                                          \
    for (int g = 0; g < 4; ++g) {                                              \
      f32x4 o1a = *(const f32x4*)(ds + ((g * 16) ^ lsw));                      \
      f32x4 o1b = *(const f32x4*)(ds + ((64 + g * 16) ^ lsw));                 \
      _Pragma("unroll")                                                        \
      for (int j = 0; j < 4; ++j) {                                            \
        O0[4*g+j] = O0[4*g+j] * a0 + o1a[j] * a1;                              \
        O1[4*g+j] = O1[4*g+j] * a0 + o1b[j] * a1;                              \
      }                                                                        \
    }                                                                          \
  }
  if (cc & 1) DUMP(r * 2 + (cc >> 1));      // cc=1 -> idx 2r, cc=3 -> idx 2r+1
  __syncthreads();
  if (!(cc & 1)) MERGE(r * 2 + (cc >> 1));  // cc=0 takes cc=1, cc=2 takes cc=3
  __syncthreads();
  if (cc == 2) DUMP(r * 2 + 1);
  __syncthreads();
  if (cc == 0) {
    MERGE(r * 2 + 1);
    float inv = 1.0f / lrun;
    float* orow = out + ((size_t)bb * NT + (size_t)qt * QT + r * 32 + lq) * 64;
#pragma unroll
    for (int g = 0; g < 4; ++g) {
      int d0 = 8 * g + (hi ? 4 : 0);
      f32x4 s0, s1;
#pragma unroll
      for (int j = 0; j < 4; ++j) { s0[j] = O0[4*g+j] * inv; s1[j] = O1[4*g+j] * inv; }
      *(f32x4*)(orow + d0) = s0;
      *(f32x4*)(orow + d0 + 32) = s1;
    }
  }
#undef DUMP
#undef MERGE
#undef STAGE_TILE
}

extern "C" void kernel_launch(void* const* d_in, const int* in_sizes, int n_in,
                              void* d_out, int out_size, void* d_ws, size_t ws_size,
                              hipStream_t stream) {
  const float* x  = (const float*)d_in[0];
  const float* Wk = (const float*)d_in[1];
  const float* bk = (const float*)d_in[2];
  const float* Wq = (const float*)d_in[3];
  const float* bq = (const float*)d_in[4];
  const float* Wv = (const float*)d_in[5];
  const float* bv = (const float*)d_in[6];
  float* out = (float*)d_out;

  const size_t NE = (size_t)NBATCH * NT * 64;
  unsigned short* ws = (unsigned short*)d_ws;
  unsigned short* khi = ws;
  unsigned short* klo = ws + NE;
  unsigned short* qhi = ws + 2 * NE;
  unsigned short* qlo = ws + 3 * NE;
  unsigned short* vt  = ws + 4 * NE;

  proj_kernel<<<dim3((NBATCH * NT) / 64), dim3(256), 0, stream>>>(
      x, Wk, bk, Wq, bq, Wv, bv, khi, klo, qhi, qlo, vt);
  attn_kernel<<<dim3(NBATCH * (NT / QT)), dim3(1024), 0, stream>>>(
      khi, klo, qhi, qlo, vt, out);
}